// Round 1
// baseline (461.933 us; speedup 1.0000x reference)
//
#include <hip/hip_runtime.h>
#include <hip/hip_bf16.h>
#include <cstdint>
#include <cstddef>

typedef unsigned short u16;
typedef short bf16x8 __attribute__((ext_vector_type(8)));
typedef float f32x4 __attribute__((ext_vector_type(4)));

#define DMs   1024
#define DINs  2048
#define LSEQ  1024
#define NST   16
#define RDT   64
#define NXD   96   /* R + 2N */

__device__ __forceinline__ u16 f2bf(float f) {
  uint32_t u = __builtin_bit_cast(uint32_t, f);
  u += 0x7FFFu + ((u >> 16) & 1u);
  return (u16)(u >> 16);
}

// ---------------- f32 -> bf16 convert (vectorized, grid-stride) ----------------
__global__ void k_cvt(const float* __restrict__ in, u16* __restrict__ out, int n4) {
  int i = blockIdx.x * blockDim.x + threadIdx.x;
  int stride = gridDim.x * blockDim.x;
  for (int j = i; j < n4; j += stride) {
    float4 v = reinterpret_cast<const float4*>(in)[j];
    ushort4 o;
    o.x = f2bf(v.x); o.y = f2bf(v.y); o.z = f2bf(v.z); o.w = f2bf(v.w);
    reinterpret_cast<ushort4*>(out)[j] = o;
  }
}

// ---------------- bf16 MFMA GEMM:  C[M][N] = A[M][K] * B[N][K]^T ----------------
// 4 waves in 2x2 layout, wave tile (TM/2)x(TN/2), 16x16x32 bf16 MFMA, BK=32.
template<int TM, int TN>
__global__ __launch_bounds__(256) void k_gemm_bf16(
    const u16* __restrict__ A, const u16* __restrict__ B, float* __restrict__ C,
    int M, int N, int K) {
  constexpr int PADR = 40;             // row stride in bf16 (pad 32->40: kills bank conflicts)
  constexpr int WTM = TM / 2, WTN = TN / 2;
  constexpr int FM = WTM / 16, FN = WTN / 16;
  __shared__ __align__(16) u16 As[TM * PADR];
  __shared__ __align__(16) u16 Bs[TN * PADR];
  const int t = threadIdx.x;
  const int lane = t & 63, w = t >> 6;
  const int m0 = blockIdx.x * TM, n0 = blockIdx.y * TN;
  const int wm = (w >> 1) * WTM, wn = (w & 1) * WTN;
  const int fr = lane & 15, g = lane >> 4;
  f32x4 acc[FM][FN] = {};
  for (int k0 = 0; k0 < K; k0 += 32) {
    __syncthreads();
#pragma unroll
    for (int i = 0; i < TM / 64; ++i) {
      int idx = t + i * 256;
      int r = idx >> 2, cg = (idx & 3) * 8;
      *(bf16x8*)&As[r * PADR + cg] = *(const bf16x8*)&A[(size_t)(m0 + r) * K + k0 + cg];
    }
#pragma unroll
    for (int i = 0; i < TN / 64; ++i) {
      int idx = t + i * 256;
      int r = idx >> 2, cg = (idx & 3) * 8;
      *(bf16x8*)&Bs[r * PADR + cg] = *(const bf16x8*)&B[(size_t)(n0 + r) * K + k0 + cg];
    }
    __syncthreads();
    bf16x8 af[FM], bfv[FN];
#pragma unroll
    for (int i = 0; i < FM; ++i)
      af[i] = *(const bf16x8*)&As[(wm + i * 16 + fr) * PADR + g * 8];
#pragma unroll
    for (int j = 0; j < FN; ++j)
      bfv[j] = *(const bf16x8*)&Bs[(wn + j * 16 + fr) * PADR + g * 8];
#pragma unroll
    for (int i = 0; i < FM; ++i)
#pragma unroll
      for (int j = 0; j < FN; ++j)
        acc[i][j] = __builtin_amdgcn_mfma_f32_16x16x32_bf16(af[i], bfv[j], acc[i][j], 0, 0, 0);
  }
  // C/D layout (verified): col = lane&15, row = (lane>>4)*4 + reg
#pragma unroll
  for (int i = 0; i < FM; ++i)
#pragma unroll
    for (int j = 0; j < FN; ++j) {
      int mb = m0 + wm + i * 16 + g * 4;
      int nn = n0 + wn + j * 16 + fr;
#pragma unroll
      for (int e = 0; e < 4; ++e)
        C[(size_t)(mb + e) * N + nn] = acc[i][j][e];
    }
}

// ---------------- causal depthwise conv (K=4) + bias + silu ----------------
__global__ __launch_bounds__(256) void k_conv(
    const float* __restrict__ xz, const float* __restrict__ cw, const float* __restrict__ cb,
    float* __restrict__ xc) {
  int d = blockIdx.x * 256 + threadIdx.x;
  int l = blockIdx.y;
  float4 wv = *(const float4*)&cw[d * 4];
  float acc = cb[d];
  const float wj[4] = {wv.x, wv.y, wv.z, wv.w};
#pragma unroll
  for (int j = 0; j < 4; ++j) {
    int ls = l - 3 + j;
    if (ls >= 0) acc += wj[j] * xz[(size_t)ls * (2 * DINs) + d];
  }
  float sg = 1.f / (1.f + __expf(-acc));
  xc[(size_t)l * DINs + d] = acc * sg;
}

// ---------------- GEMM2: x_dbl[L][96] = xc[L][2048] * W_x[96][2048]^T, K-split=4 ----------------
__global__ __launch_bounds__(256) void k_gemm2(
    const float* __restrict__ xc, const float* __restrict__ Wx, float* __restrict__ part) {
  int t = threadIdx.x;
  int c = t & 127, rh = t >> 7;
  int l0 = blockIdx.x * 8 + rh * 4;
  int ks = blockIdx.y;                 // 0..3  (K-chunk 512)
  int cc = c < 96 ? c : 95;
  const float* wrow = Wx + (size_t)cc * DINs + ks * 512;
  const float* xb0 = xc + (size_t)l0 * DINs + ks * 512;
  float a0 = 0.f, a1 = 0.f, a2 = 0.f, a3 = 0.f;
  for (int k = 0; k < 512; k += 4) {
    float4 wv = *(const float4*)&wrow[k];
    float4 x0 = *(const float4*)&xb0[k];
    float4 x1 = *(const float4*)&xb0[k + DINs];
    float4 x2 = *(const float4*)&xb0[k + 2 * DINs];
    float4 x3 = *(const float4*)&xb0[k + 3 * DINs];
    a0 += wv.x * x0.x + wv.y * x0.y + wv.z * x0.z + wv.w * x0.w;
    a1 += wv.x * x1.x + wv.y * x1.y + wv.z * x1.z + wv.w * x1.w;
    a2 += wv.x * x2.x + wv.y * x2.y + wv.z * x2.z + wv.w * x2.w;
    a3 += wv.x * x3.x + wv.y * x3.y + wv.z * x3.z + wv.w * x3.w;
  }
  if (c < 96) {
    float* p = part + (size_t)ks * (LSEQ * NXD) + (size_t)l0 * NXD + c;
    p[0 * NXD] = a0; p[1 * NXD] = a1; p[2 * NXD] = a2; p[3 * NXD] = a3;
  }
}

__global__ void k_red4(const float* __restrict__ part, float* __restrict__ xdbl) {
  int i = blockIdx.x * 256 + threadIdx.x;
  const int S = LSEQ * NXD;
  xdbl[i] = part[i] + part[i + S] + part[i + 2 * S] + part[i + 3 * S];
}

// ---------------- GEMM3: dt[L][2048] = softplus(x_dbl[:, :64] * W_dt^T + b_dt) ----------------
__global__ __launch_bounds__(256) void k_gemm3(
    const float* __restrict__ xdbl, const float* __restrict__ Wdt,
    const float* __restrict__ bdt, float* __restrict__ dtf) {
  int d = blockIdx.x * 256 + threadIdx.x;
  int r0 = blockIdx.y * 16;
  float wreg[64];
#pragma unroll
  for (int i = 0; i < 16; ++i)
    *(float4*)&wreg[i * 4] = *(const float4*)&Wdt[(size_t)d * RDT + i * 4];
  float bv = bdt[d];
  for (int r = r0; r < r0 + 16; ++r) {
    const float* xrow = xdbl + (size_t)r * NXD;
    float acc = bv;
#pragma unroll
    for (int i = 0; i < 16; ++i) {
      float4 xv = *(const float4*)&xrow[i * 4];
      acc += xv.x * wreg[i * 4] + xv.y * wreg[i * 4 + 1] + xv.z * wreg[i * 4 + 2] + xv.w * wreg[i * 4 + 3];
    }
    float sp = acc > 20.f ? acc : logf(1.f + __expf(acc));
    dtf[(size_t)r * DINs + d] = sp;
  }
}

// ---------------- selective scan + y + gate, fused ----------------
// Block: 256 threads = 4 waves, 16 d-channels. Wave = 4 d x 16 n lanes.
__global__ __launch_bounds__(256) void k_scan(
    const float* __restrict__ dtf, const float* __restrict__ xdbl,
    const float* __restrict__ xc, const float* __restrict__ xz,
    const float* __restrict__ Alog, const float* __restrict__ Dp,
    u16* __restrict__ ybar) {
  __shared__ float s_dt[64][16], s_xc[64][16], s_z[64][16], s_bc[64][32];
  const int t = threadIdx.x;
  const int lane = t & 63, w = t >> 6;
  const int d0 = blockIdx.x * 16;
  const int widx = w * 4 + (lane >> 4);   // local d: 0..15
  const int d = d0 + widx;
  const int n = lane & 15;
  const float a_coef = -__expf(Alog[(size_t)d * NST + n]);
  const float Dv = Dp[d];
  float h = 0.f;
  for (int l0 = 0; l0 < LSEQ; l0 += 64) {
    __syncthreads();
#pragma unroll
    for (int i = 0; i < 4; ++i) {
      int idx = t + i * 256;
      int r = idx >> 4, c = idx & 15;
      s_dt[r][c] = dtf[(size_t)(l0 + r) * DINs + d0 + c];
      s_xc[r][c] = xc[(size_t)(l0 + r) * DINs + d0 + c];
      s_z[r][c]  = xz[(size_t)(l0 + r) * (2 * DINs) + DINs + d0 + c];
    }
#pragma unroll
    for (int i = 0; i < 8; ++i) {
      int idx = t + i * 256;
      int r = idx >> 5, c = idx & 31;
      s_bc[r][c] = xdbl[(size_t)(l0 + r) * NXD + RDT + c];
    }
    __syncthreads();
#pragma unroll 8
    for (int l = 0; l < 64; ++l) {
      float dtv = s_dt[l][widx];
      float xcv = s_xc[l][widx];
      float bm = s_bc[l][n];
      float cm = s_bc[l][16 + n];
      float ab = __expf(dtv * a_coef);
      h = ab * h + (dtv * bm) * xcv;
      float yp = h * cm;
      yp += __shfl_xor(yp, 1);
      yp += __shfl_xor(yp, 2);
      yp += __shfl_xor(yp, 4);
      yp += __shfl_xor(yp, 8);
      if (n == 0) {
        float y = yp + Dv * xcv;
        float zv = s_z[l][widx];
        float sz = zv / (1.f + __expf(-zv));
        ybar[(size_t)(l0 + l) * DINs + d] = f2bf(y * sz);
      }
    }
  }
}

// ---------------- launch ----------------
extern "C" void kernel_launch(void* const* d_in, const int* in_sizes, int n_in,
                              void* d_out, int out_size, void* d_ws, size_t ws_size,
                              hipStream_t stream) {
  (void)in_sizes; (void)n_in; (void)out_size; (void)ws_size;
  const float* x      = (const float*)d_in[0];
  const float* W_in   = (const float*)d_in[1];
  const float* conv_w = (const float*)d_in[2];
  const float* conv_b = (const float*)d_in[3];
  const float* W_x    = (const float*)d_in[4];
  const float* W_dt   = (const float*)d_in[5];
  const float* b_dt   = (const float*)d_in[6];
  const float* A_log  = (const float*)d_in[7];
  const float* D_par  = (const float*)d_in[8];
  const float* W_out  = (const float*)d_in[9];
  float* out = (float*)d_out;

  char* wsb = (char*)d_ws;
  u16*   x_bf    = (u16*)(wsb + 0);                    // 2 MB
  u16*   win_bf  = (u16*)(wsb + (size_t)(2u << 20));   // 8 MB
  u16*   wout_bf = (u16*)(wsb + (size_t)(10u << 20));  // 4 MB
  float* xz      = (float*)(wsb + (size_t)(14u << 20)); // 16 MB
  float* xc      = (float*)(wsb + (size_t)(30u << 20)); // 8 MB
  float* part    = (float*)(wsb + (size_t)(38u << 20)); // 1.5 MB
  float* xdbl    = (float*)(wsb + (size_t)(40u << 20)); // 384 KB
  float* dtf     = (float*)(wsb + (size_t)(41u << 20)); // 8 MB
  u16*   ybar    = (u16*)(wsb + (size_t)(49u << 20));   // 4 MB  (total 53 MB)

  k_cvt<<<2048, 256, 0, stream>>>(x, x_bf, (DMs * LSEQ) / 4);
  k_cvt<<<2048, 256, 0, stream>>>(W_in, win_bf, (2 * DINs * DMs) / 4);
  k_cvt<<<2048, 256, 0, stream>>>(W_out, wout_bf, (DMs * DINs) / 4);

  // GEMM1: xz[L][4096] = x * W_in^T
  k_gemm_bf16<128, 128><<<dim3(LSEQ / 128, (2 * DINs) / 128), 256, 0, stream>>>(
      x_bf, win_bf, xz, LSEQ, 2 * DINs, DMs);

  k_conv<<<dim3(DINs / 256, LSEQ), 256, 0, stream>>>(xz, conv_w, conv_b, xc);

  k_gemm2<<<dim3(LSEQ / 8, 4), 256, 0, stream>>>(xc, W_x, part);
  k_red4<<<(LSEQ * NXD) / 256, 256, 0, stream>>>(part, xdbl);

  k_gemm3<<<dim3(DINs / 256, LSEQ / 16), 256, 0, stream>>>(xdbl, W_dt, b_dt, dtf);

  k_scan<<<DINs / 16, 256, 0, stream>>>(dtf, xdbl, xc, xz, A_log, D_par, ybar);

  // GEMM4: out[L][1024] = ybar * W_out^T
  k_gemm_bf16<64, 64><<<dim3(LSEQ / 64, DMs / 64), 256, 0, stream>>>(
      ybar, wout_bf, out, LSEQ, DMs, DINs);
}

// Round 2
// 191.798 us; speedup vs baseline: 2.4084x; 2.4084x over previous
//
#include <hip/hip_runtime.h>
#include <hip/hip_bf16.h>
#include <cstdint>
#include <cstddef>

typedef unsigned short u16;
typedef short bf16x8 __attribute__((ext_vector_type(8)));
typedef float f32x4 __attribute__((ext_vector_type(4)));

#define DMs   1024
#define DINs  2048
#define LSEQ  1024
#define NST   16
#define RDT   64
#define NXD   96   /* R + 2N */
#define CL    16   /* scan chunk length */
#define NC    64   /* number of chunks */
#define NSTATE (DINs * NST)   /* 32768 */

__device__ __forceinline__ u16 f2bf(float f) {
  uint32_t u = __builtin_bit_cast(uint32_t, f);
  u += 0x7FFFu + ((u >> 16) & 1u);
  return (u16)(u >> 16);
}

// ---------------- f32 -> bf16 convert (vectorized, grid-stride) ----------------
__global__ void k_cvt(const float* __restrict__ in, u16* __restrict__ out, int n4) {
  int i = blockIdx.x * blockDim.x + threadIdx.x;
  int stride = gridDim.x * blockDim.x;
  for (int j = i; j < n4; j += stride) {
    float4 v = reinterpret_cast<const float4*>(in)[j];
    ushort4 o;
    o.x = f2bf(v.x); o.y = f2bf(v.y); o.z = f2bf(v.z); o.w = f2bf(v.w);
    reinterpret_cast<ushort4*>(out)[j] = o;
  }
}

// ---------------- bf16 MFMA GEMM:  C[M][N] = A[M][K] * B[N][K]^T ----------------
template<int TM, int TN>
__global__ __launch_bounds__(256) void k_gemm_bf16(
    const u16* __restrict__ A, const u16* __restrict__ B, float* __restrict__ C,
    int M, int N, int K) {
  constexpr int PADR = 40;
  constexpr int WTM = TM / 2, WTN = TN / 2;
  constexpr int FM = WTM / 16, FN = WTN / 16;
  __shared__ __align__(16) u16 As[TM * PADR];
  __shared__ __align__(16) u16 Bs[TN * PADR];
  const int t = threadIdx.x;
  const int lane = t & 63, w = t >> 6;
  const int m0 = blockIdx.x * TM, n0 = blockIdx.y * TN;
  const int wm = (w >> 1) * WTM, wn = (w & 1) * WTN;
  const int fr = lane & 15, g = lane >> 4;
  f32x4 acc[FM][FN] = {};
  for (int k0 = 0; k0 < K; k0 += 32) {
    __syncthreads();
#pragma unroll
    for (int i = 0; i < TM / 64; ++i) {
      int idx = t + i * 256;
      int r = idx >> 2, cg = (idx & 3) * 8;
      *(bf16x8*)&As[r * PADR + cg] = *(const bf16x8*)&A[(size_t)(m0 + r) * K + k0 + cg];
    }
#pragma unroll
    for (int i = 0; i < TN / 64; ++i) {
      int idx = t + i * 256;
      int r = idx >> 2, cg = (idx & 3) * 8;
      *(bf16x8*)&Bs[r * PADR + cg] = *(const bf16x8*)&B[(size_t)(n0 + r) * K + k0 + cg];
    }
    __syncthreads();
    bf16x8 af[FM], bfv[FN];
#pragma unroll
    for (int i = 0; i < FM; ++i)
      af[i] = *(const bf16x8*)&As[(wm + i * 16 + fr) * PADR + g * 8];
#pragma unroll
    for (int j = 0; j < FN; ++j)
      bfv[j] = *(const bf16x8*)&Bs[(wn + j * 16 + fr) * PADR + g * 8];
#pragma unroll
    for (int i = 0; i < FM; ++i)
#pragma unroll
      for (int j = 0; j < FN; ++j)
        acc[i][j] = __builtin_amdgcn_mfma_f32_16x16x32_bf16(af[i], bfv[j], acc[i][j], 0, 0, 0);
  }
#pragma unroll
  for (int i = 0; i < FM; ++i)
#pragma unroll
    for (int j = 0; j < FN; ++j) {
      int mb = m0 + wm + i * 16 + g * 4;
      int nn = n0 + wn + j * 16 + fr;
#pragma unroll
      for (int e = 0; e < 4; ++e)
        C[(size_t)(mb + e) * N + nn] = acc[i][j][e];
    }
}

// ---------------- causal depthwise conv (K=4) + bias + silu ----------------
__global__ __launch_bounds__(256) void k_conv(
    const float* __restrict__ xz, const float* __restrict__ cw, const float* __restrict__ cb,
    float* __restrict__ xc) {
  int d = blockIdx.x * 256 + threadIdx.x;
  int l = blockIdx.y;
  float4 wv = *(const float4*)&cw[d * 4];
  float acc = cb[d];
  const float wj[4] = {wv.x, wv.y, wv.z, wv.w};
#pragma unroll
  for (int j = 0; j < 4; ++j) {
    int ls = l - 3 + j;
    if (ls >= 0) acc += wj[j] * xz[(size_t)ls * (2 * DINs) + d];
  }
  float sg = 1.f / (1.f + __expf(-acc));
  xc[(size_t)l * DINs + d] = acc * sg;
}

// ---------------- GEMM2: x_dbl[L][96] = xc[L][2048] * W_x[96][2048]^T, K-split=4 ----------------
__global__ __launch_bounds__(256) void k_gemm2(
    const float* __restrict__ xc, const float* __restrict__ Wx, float* __restrict__ part) {
  int t = threadIdx.x;
  int c = t & 127, rh = t >> 7;
  int l0 = blockIdx.x * 8 + rh * 4;
  int ks = blockIdx.y;
  int cc = c < 96 ? c : 95;
  const float* wrow = Wx + (size_t)cc * DINs + ks * 512;
  const float* xb0 = xc + (size_t)l0 * DINs + ks * 512;
  float a0 = 0.f, a1 = 0.f, a2 = 0.f, a3 = 0.f;
  for (int k = 0; k < 512; k += 4) {
    float4 wv = *(const float4*)&wrow[k];
    float4 x0 = *(const float4*)&xb0[k];
    float4 x1 = *(const float4*)&xb0[k + DINs];
    float4 x2 = *(const float4*)&xb0[k + 2 * DINs];
    float4 x3 = *(const float4*)&xb0[k + 3 * DINs];
    a0 += wv.x * x0.x + wv.y * x0.y + wv.z * x0.z + wv.w * x0.w;
    a1 += wv.x * x1.x + wv.y * x1.y + wv.z * x1.z + wv.w * x1.w;
    a2 += wv.x * x2.x + wv.y * x2.y + wv.z * x2.z + wv.w * x2.w;
    a3 += wv.x * x3.x + wv.y * x3.y + wv.z * x3.z + wv.w * x3.w;
  }
  if (c < 96) {
    float* p = part + (size_t)ks * (LSEQ * NXD) + (size_t)l0 * NXD + c;
    p[0 * NXD] = a0; p[1 * NXD] = a1; p[2 * NXD] = a2; p[3 * NXD] = a3;
  }
}

__global__ void k_red4(const float* __restrict__ part, float* __restrict__ xdbl) {
  int i = blockIdx.x * 256 + threadIdx.x;
  const int S = LSEQ * NXD;
  xdbl[i] = part[i] + part[i + S] + part[i + 2 * S] + part[i + 3 * S];
}

// ---------------- GEMM3: dt[L][2048] = softplus(x_dbl[:, :64] * W_dt^T + b_dt) ----------------
__global__ __launch_bounds__(256) void k_gemm3(
    const float* __restrict__ xdbl, const float* __restrict__ Wdt,
    const float* __restrict__ bdt, float* __restrict__ dtf) {
  int d = blockIdx.x * 256 + threadIdx.x;
  int r0 = blockIdx.y * 16;
  float wreg[64];
#pragma unroll
  for (int i = 0; i < 16; ++i)
    *(float4*)&wreg[i * 4] = *(const float4*)&Wdt[(size_t)d * RDT + i * 4];
  float bv = bdt[d];
  for (int r = r0; r < r0 + 16; ++r) {
    const float* xrow = xdbl + (size_t)r * NXD;
    float acc = bv;
#pragma unroll
    for (int i = 0; i < 16; ++i) {
      float4 xv = *(const float4*)&xrow[i * 4];
      acc += xv.x * wreg[i * 4] + xv.y * wreg[i * 4 + 1] + xv.z * wreg[i * 4 + 2] + xv.w * wreg[i * 4 + 3];
    }
    float sp = acc > 20.f ? acc : logf(1.f + __expf(acc));
    dtf[(size_t)r * DINs + d] = sp;
  }
}

// ---------------- Pass A: chunk-local scan (h_in = 0) + chunk A-product ----------------
// thread = one d; 16 n-states in registers. grid (DINs/256, NC).
__global__ __launch_bounds__(256) void k_scanA(
    const float* __restrict__ dtf, const float* __restrict__ xdbl,
    const float* __restrict__ xc, const float* __restrict__ Alog,
    float* __restrict__ aprod, float* __restrict__ hout) {
  __shared__ float sB[CL][NST];
  const int t = threadIdx.x;
  const int d = blockIdx.x * 256 + t;
  const int c = blockIdx.y;
  {
    int l = t >> 4, n = t & 15;   // 256 threads cover 16x16
    sB[l][n] = xdbl[(size_t)(c * CL + l) * NXD + RDT + n];
  }
  __syncthreads();
  float ac[NST];
#pragma unroll
  for (int i = 0; i < 4; ++i) {
    float4 v = *(const float4*)&Alog[(size_t)d * NST + i * 4];
    ac[i * 4 + 0] = -__expf(v.x); ac[i * 4 + 1] = -__expf(v.y);
    ac[i * 4 + 2] = -__expf(v.z); ac[i * 4 + 3] = -__expf(v.w);
  }
  float h[NST] = {};
  float dtsum = 0.f;
#pragma unroll
  for (int l = 0; l < CL; ++l) {
    float dtv = dtf[(size_t)(c * CL + l) * DINs + d];
    float xcv = xc[(size_t)(c * CL + l) * DINs + d];
    dtsum += dtv;
    float dx = dtv * xcv;
#pragma unroll
    for (int n = 0; n < NST; ++n) {
      float ab = __expf(dtv * ac[n]);
      h[n] = ab * h[n] + dx * sB[l][n];
    }
  }
  size_t base = (size_t)c * NSTATE + (size_t)d * NST;
#pragma unroll
  for (int n = 0; n < NST; ++n) {
    hout[base + n] = h[n];
    aprod[base + n] = __expf(dtsum * ac[n]);
  }
}

// ---------------- Pass B: combine chunk summaries; aprod becomes hpref in-place ----------------
__global__ __launch_bounds__(256) void k_scanB(
    float* __restrict__ aprod, const float* __restrict__ hout) {
  int s = blockIdx.x * 256 + threadIdx.x;   // state index 0..NSTATE-1
  float h = 0.f;
#pragma unroll 8
  for (int c = 0; c < NC; ++c) {
    size_t idx = (size_t)c * NSTATE + s;
    float a = aprod[idx];
    float b = hout[idx];
    aprod[idx] = h;            // prefix BEFORE chunk c (same thread, same addr: race-free)
    h = a * h + b;
  }
}

// ---------------- Pass C: recompute with true h_in, fuse y + D*xc + silu(z) gate ----------------
__global__ __launch_bounds__(256) void k_scanC(
    const float* __restrict__ dtf, const float* __restrict__ xdbl,
    const float* __restrict__ xc, const float* __restrict__ xz,
    const float* __restrict__ Alog, const float* __restrict__ Dp,
    const float* __restrict__ hpref, u16* __restrict__ ybar) {
  __shared__ float sB[CL][NST], sC[CL][NST];
  const int t = threadIdx.x;
  const int d = blockIdx.x * 256 + t;
  const int c = blockIdx.y;
  {
    int l = t >> 4, n = t & 15;
    sB[l][n] = xdbl[(size_t)(c * CL + l) * NXD + RDT + n];
    sC[l][n] = xdbl[(size_t)(c * CL + l) * NXD + RDT + NST + n];
  }
  __syncthreads();
  float ac[NST];
#pragma unroll
  for (int i = 0; i < 4; ++i) {
    float4 v = *(const float4*)&Alog[(size_t)d * NST + i * 4];
    ac[i * 4 + 0] = -__expf(v.x); ac[i * 4 + 1] = -__expf(v.y);
    ac[i * 4 + 2] = -__expf(v.z); ac[i * 4 + 3] = -__expf(v.w);
  }
  float h[NST];
  size_t base = (size_t)c * NSTATE + (size_t)d * NST;
#pragma unroll
  for (int i = 0; i < 4; ++i)
    *(float4*)&h[i * 4] = *(const float4*)&hpref[base + i * 4];
  const float Dv = Dp[d];
#pragma unroll
  for (int l = 0; l < CL; ++l) {
    float dtv = dtf[(size_t)(c * CL + l) * DINs + d];
    float xcv = xc[(size_t)(c * CL + l) * DINs + d];
    float zv  = xz[(size_t)(c * CL + l) * (2 * DINs) + DINs + d];
    float dx = dtv * xcv;
    float y0 = Dv * xcv, y1 = 0.f, y2 = 0.f, y3 = 0.f;
#pragma unroll
    for (int n = 0; n < NST; n += 4) {
      float ab0 = __expf(dtv * ac[n]);
      float ab1 = __expf(dtv * ac[n + 1]);
      float ab2 = __expf(dtv * ac[n + 2]);
      float ab3 = __expf(dtv * ac[n + 3]);
      h[n]     = ab0 * h[n]     + dx * sB[l][n];
      h[n + 1] = ab1 * h[n + 1] + dx * sB[l][n + 1];
      h[n + 2] = ab2 * h[n + 2] + dx * sB[l][n + 2];
      h[n + 3] = ab3 * h[n + 3] + dx * sB[l][n + 3];
      y0 += h[n] * sC[l][n];
      y1 += h[n + 1] * sC[l][n + 1];
      y2 += h[n + 2] * sC[l][n + 2];
      y3 += h[n + 3] * sC[l][n + 3];
    }
    float y = (y0 + y1) + (y2 + y3);
    float sz = zv / (1.f + __expf(-zv));
    ybar[(size_t)(c * CL + l) * DINs + d] = f2bf(y * sz);
  }
}

// ---------------- launch ----------------
extern "C" void kernel_launch(void* const* d_in, const int* in_sizes, int n_in,
                              void* d_out, int out_size, void* d_ws, size_t ws_size,
                              hipStream_t stream) {
  (void)in_sizes; (void)n_in; (void)out_size; (void)ws_size;
  const float* x      = (const float*)d_in[0];
  const float* W_in   = (const float*)d_in[1];
  const float* conv_w = (const float*)d_in[2];
  const float* conv_b = (const float*)d_in[3];
  const float* W_x    = (const float*)d_in[4];
  const float* W_dt   = (const float*)d_in[5];
  const float* b_dt   = (const float*)d_in[6];
  const float* A_log  = (const float*)d_in[7];
  const float* D_par  = (const float*)d_in[8];
  const float* W_out  = (const float*)d_in[9];
  float* out = (float*)d_out;

  char* wsb = (char*)d_ws;
  u16*   x_bf    = (u16*)(wsb + 0);                     // 2 MB
  u16*   win_bf  = (u16*)(wsb + (size_t)(2u << 20));    // 8 MB
  u16*   wout_bf = (u16*)(wsb + (size_t)(10u << 20));   // 4 MB
  float* xz      = (float*)(wsb + (size_t)(14u << 20)); // 16 MB
  float* xc      = (float*)(wsb + (size_t)(30u << 20)); // 8 MB
  float* part    = (float*)(wsb + (size_t)(38u << 20)); // 1.5 MB
  float* xdbl    = (float*)(wsb + (size_t)(40u << 20)); // 384 KB
  float* dtf     = (float*)(wsb + (size_t)(41u << 20)); // 8 MB
  u16*   ybar    = (u16*)(wsb + (size_t)(49u << 20));   // 4 MB
  float* aprod   = (float*)(wsb + (size_t)(53u << 20)); // 8 MB (becomes hpref)
  float* hout    = (float*)(wsb + (size_t)(61u << 20)); // 8 MB -> total 69 MB

  k_cvt<<<2048, 256, 0, stream>>>(x, x_bf, (DMs * LSEQ) / 4);
  k_cvt<<<2048, 256, 0, stream>>>(W_in, win_bf, (2 * DINs * DMs) / 4);
  k_cvt<<<2048, 256, 0, stream>>>(W_out, wout_bf, (DMs * DINs) / 4);

  // GEMM1: xz[L][4096] = x * W_in^T
  k_gemm_bf16<128, 128><<<dim3(LSEQ / 128, (2 * DINs) / 128), 256, 0, stream>>>(
      x_bf, win_bf, xz, LSEQ, 2 * DINs, DMs);

  k_conv<<<dim3(DINs / 256, LSEQ), 256, 0, stream>>>(xz, conv_w, conv_b, xc);

  k_gemm2<<<dim3(LSEQ / 8, 4), 256, 0, stream>>>(xc, W_x, part);
  k_red4<<<(LSEQ * NXD) / 256, 256, 0, stream>>>(part, xdbl);

  k_gemm3<<<dim3(DINs / 256, LSEQ / 16), 256, 0, stream>>>(xdbl, W_dt, b_dt, dtf);

  // chunked scan
  k_scanA<<<dim3(DINs / 256, NC), 256, 0, stream>>>(dtf, xdbl, xc, A_log, aprod, hout);
  k_scanB<<<NSTATE / 256, 256, 0, stream>>>(aprod, hout);
  k_scanC<<<dim3(DINs / 256, NC), 256, 0, stream>>>(dtf, xdbl, xc, xz, A_log, D_par,
                                                    aprod, ybar);

  // GEMM4: out[L][1024] = ybar * W_out^T
  k_gemm_bf16<64, 64><<<dim3(LSEQ / 64, DMs / 64), 256, 0, stream>>>(
      ybar, wout_bf, out, LSEQ, DMs, DINs);
}

// Round 3
// 182.071 us; speedup vs baseline: 2.5371x; 1.0534x over previous
//
#include <hip/hip_runtime.h>
#include <hip/hip_bf16.h>
#include <cstdint>
#include <cstddef>

typedef unsigned short u16;
typedef short bf16x8 __attribute__((ext_vector_type(8)));
typedef float f32x4 __attribute__((ext_vector_type(4)));

typedef __attribute__((address_space(1))) void gvoid;
typedef __attribute__((address_space(3))) void lvoid;

#define DMs   1024
#define DINs  2048
#define LSEQ  1024
#define NST   16
#define RDT   64
#define NXD   96   /* R + 2N */
#define CL    16   /* scan chunk length */
#define NC    64   /* number of chunks */
#define NSTATE (DINs * NST)   /* 32768 */
#define K2    6144 /* split-bf16 GEMM2 K' = 3*2048 */

__device__ __forceinline__ u16 f2bf(float f) {
  uint32_t u = __builtin_bit_cast(uint32_t, f);
  u += 0x7FFFu + ((u >> 16) & 1u);
  return (u16)(u >> 16);
}
__device__ __forceinline__ float bf2f(u16 h) {
  return __builtin_bit_cast(float, (uint32_t)h << 16);
}
__device__ __forceinline__ void gload_lds16(const u16* g, u16* l) {
  __builtin_amdgcn_global_load_lds((gvoid*)g, (lvoid*)l, 16, 0, 0);
}

// ---------------- f32 -> bf16 convert (vectorized, grid-stride) ----------------
__global__ void k_cvt(const float* __restrict__ in, u16* __restrict__ out, int n4) {
  int i = blockIdx.x * blockDim.x + threadIdx.x;
  int stride = gridDim.x * blockDim.x;
  for (int j = i; j < n4; j += stride) {
    float4 v = reinterpret_cast<const float4*>(in)[j];
    ushort4 o;
    o.x = f2bf(v.x); o.y = f2bf(v.y); o.z = f2bf(v.z); o.w = f2bf(v.w);
    reinterpret_cast<ushort4*>(out)[j] = o;
  }
}

// ---------------- m97-style MFMA GEMM with global_load_lds ----------------
// C[M][N] = A[M][K] * B[N][K]^T.  Linear LDS [rows][32], BK=32, 4 waves 2x2.
template<int TM, int TN>
__global__ __launch_bounds__(256) void k_gemm_lds(
    const u16* __restrict__ A, const u16* __restrict__ B, float* __restrict__ C,
    int M, int N, int K) {
  constexpr int WTM = TM / 2, WTN = TN / 2;
  constexpr int FM = WTM / 16, FN = WTN / 16;
  __shared__ __align__(16) u16 As[TM * 32];
  __shared__ __align__(16) u16 Bs[TN * 32];
  const int t = threadIdx.x;
  const int lane = t & 63, w = t >> 6;
  const int m0 = blockIdx.x * TM, n0 = blockIdx.y * TN;
  const int wm = (w >> 1) * WTM, wn = (w & 1) * WTN;
  const int fr = lane & 15, g = lane >> 4;
  const int ar = t >> 2, acg = (t & 3) * 8;
  f32x4 acc[FM][FN] = {};
  for (int k0 = 0; k0 < K; k0 += 32) {
    __syncthreads();
#pragma unroll
    for (int i = 0; i < TM / 64; ++i)
      gload_lds16(&A[(size_t)(m0 + ar + i * 64) * K + k0 + acg], &As[(t + i * 256) * 8]);
#pragma unroll
    for (int i = 0; i < TN / 64; ++i)
      gload_lds16(&B[(size_t)(n0 + ar + i * 64) * K + k0 + acg], &Bs[(t + i * 256) * 8]);
    __syncthreads();
    bf16x8 af[FM], bfv[FN];
#pragma unroll
    for (int i = 0; i < FM; ++i)
      af[i] = *(const bf16x8*)&As[(wm + i * 16 + fr) * 32 + g * 8];
#pragma unroll
    for (int j = 0; j < FN; ++j)
      bfv[j] = *(const bf16x8*)&Bs[(wn + j * 16 + fr) * 32 + g * 8];
#pragma unroll
    for (int i = 0; i < FM; ++i)
#pragma unroll
      for (int j = 0; j < FN; ++j)
        acc[i][j] = __builtin_amdgcn_mfma_f32_16x16x32_bf16(af[i], bfv[j], acc[i][j], 0, 0, 0);
  }
  // C/D layout: col = lane&15, row = (lane>>4)*4 + reg
#pragma unroll
  for (int i = 0; i < FM; ++i)
#pragma unroll
    for (int j = 0; j < FN; ++j) {
      int mb = m0 + wm + i * 16 + g * 4;
      int nn = n0 + wn + j * 16 + fr;
#pragma unroll
      for (int e = 0; e < 4; ++e)
        C[(size_t)(mb + e) * N + nn] = acc[i][j][e];
    }
}

// ---------------- causal depthwise conv (K=4) + bias + silu; emits xc f32 and A2 hi/lo/hi bf16 ----------------
__global__ __launch_bounds__(256) void k_conv(
    const float* __restrict__ xz, const float* __restrict__ cw, const float* __restrict__ cb,
    float* __restrict__ xc, u16* __restrict__ a2) {
  int d = blockIdx.x * 256 + threadIdx.x;
  int l = blockIdx.y;
  float4 wv = *(const float4*)&cw[d * 4];
  float acc = cb[d];
  const float wj[4] = {wv.x, wv.y, wv.z, wv.w};
#pragma unroll
  for (int j = 0; j < 4; ++j) {
    int ls = l - 3 + j;
    if (ls >= 0) acc += wj[j] * xz[(size_t)ls * (2 * DINs) + d];
  }
  float sg = 1.f / (1.f + __expf(-acc));
  float v = acc * sg;
  xc[(size_t)l * DINs + d] = v;
  u16 hi = f2bf(v);
  u16 lo = f2bf(v - bf2f(hi));
  size_t base = (size_t)l * K2;
  a2[base + d] = hi;
  a2[base + DINs + d] = lo;
  a2[base + 2 * DINs + d] = hi;
}

// ---------------- B2 prep: [hiW | hiW | loW], 96 rows x 6144 ----------------
__global__ void k_prepB(const float* __restrict__ Wx, u16* __restrict__ b2) {
  int i = blockIdx.x * 256 + threadIdx.x;   // 0 .. 96*2048-1
  int c = i >> 11, k = i & 2047;
  float v = Wx[i];
  u16 hi = f2bf(v);
  u16 lo = f2bf(v - bf2f(hi));
  size_t base = (size_t)c * K2;
  b2[base + k] = hi;
  b2[base + DINs + k] = hi;
  b2[base + 2 * DINs + k] = lo;
}

// ---------------- GEMM2 (split-bf16 MFMA): part[ks][L][96] over K-chunk 1536 ----------------
__global__ __launch_bounds__(256) void k_gemm2m(
    const u16* __restrict__ A2, const u16* __restrict__ B2, float* __restrict__ part) {
  constexpr int PADR = 40;
  __shared__ __align__(16) u16 As[64 * PADR];
  __shared__ __align__(16) u16 Bs[96 * PADR];
  const int t = threadIdx.x;
  const int lane = t & 63, w = t >> 6;
  const int m0 = blockIdx.x * 64;
  const int ks = blockIdx.y;
  const int kbeg = ks * (K2 / 4);
  const int wm = (w >> 1) * 32, wn = (w & 1) * 48;
  const int fr = lane & 15, g = lane >> 4;
  f32x4 acc[2][3] = {};
  for (int kk = 0; kk < K2 / 4; kk += 32) {
    int k0 = kbeg + kk;
    __syncthreads();
    {
      int r = t >> 2, c = (t & 3) * 8;
      *(bf16x8*)&As[r * PADR + c] = *(const bf16x8*)&A2[(size_t)(m0 + r) * K2 + k0 + c];
    }
#pragma unroll
    for (int i = 0; i < 2; ++i) {
      int idx = t + i * 256;
      if (idx < 384) {
        int r = idx >> 2, c = (idx & 3) * 8;
        *(bf16x8*)&Bs[r * PADR + c] = *(const bf16x8*)&B2[(size_t)r * K2 + k0 + c];
      }
    }
    __syncthreads();
    bf16x8 af[2], bfv[3];
#pragma unroll
    for (int i = 0; i < 2; ++i)
      af[i] = *(const bf16x8*)&As[(wm + i * 16 + fr) * PADR + g * 8];
#pragma unroll
    for (int j = 0; j < 3; ++j)
      bfv[j] = *(const bf16x8*)&Bs[(wn + j * 16 + fr) * PADR + g * 8];
#pragma unroll
    for (int i = 0; i < 2; ++i)
#pragma unroll
      for (int j = 0; j < 3; ++j)
        acc[i][j] = __builtin_amdgcn_mfma_f32_16x16x32_bf16(af[i], bfv[j], acc[i][j], 0, 0, 0);
  }
  float* P = part + (size_t)ks * (LSEQ * NXD);
#pragma unroll
  for (int i = 0; i < 2; ++i)
#pragma unroll
    for (int j = 0; j < 3; ++j) {
      int mb = m0 + wm + i * 16 + g * 4;
      int nn = wn + j * 16 + fr;
#pragma unroll
      for (int e = 0; e < 4; ++e)
        P[(size_t)(mb + e) * NXD + nn] = acc[i][j][e];
    }
}

__global__ void k_red4(const float* __restrict__ part, float* __restrict__ xdbl) {
  int i = blockIdx.x * 256 + threadIdx.x;
  const int S = LSEQ * NXD;
  xdbl[i] = part[i] + part[i + S] + part[i + 2 * S] + part[i + 3 * S];
}

// ---------------- GEMM3: dt[L][2048] = softplus(x_dbl[:, :64] * W_dt^T + b_dt) ----------------
__global__ __launch_bounds__(256) void k_gemm3(
    const float* __restrict__ xdbl, const float* __restrict__ Wdt,
    const float* __restrict__ bdt, float* __restrict__ dtf) {
  int d = blockIdx.x * 256 + threadIdx.x;
  int r0 = blockIdx.y * 16;
  float wreg[64];
#pragma unroll
  for (int i = 0; i < 16; ++i)
    *(float4*)&wreg[i * 4] = *(const float4*)&Wdt[(size_t)d * RDT + i * 4];
  float bv = bdt[d];
  for (int r = r0; r < r0 + 16; ++r) {
    const float* xrow = xdbl + (size_t)r * NXD;
    float acc = bv;
#pragma unroll
    for (int i = 0; i < 16; ++i) {
      float4 xv = *(const float4*)&xrow[i * 4];
      acc += xv.x * wreg[i * 4] + xv.y * wreg[i * 4 + 1] + xv.z * wreg[i * 4 + 2] + xv.w * wreg[i * 4 + 3];
    }
    float sp = acc > 20.f ? acc : logf(1.f + __expf(acc));
    dtf[(size_t)r * DINs + d] = sp;
  }
}

// ---------------- Pass A: chunk-local scan (h_in = 0) + chunk A-product ----------------
__global__ __launch_bounds__(256) void k_scanA(
    const float* __restrict__ dtf, const float* __restrict__ xdbl,
    const float* __restrict__ xc, const float* __restrict__ Alog,
    float* __restrict__ aprod, float* __restrict__ hout) {
  __shared__ float sB[CL][NST];
  const int t = threadIdx.x;
  const int d = blockIdx.x * 256 + t;
  const int c = blockIdx.y;
  {
    int l = t >> 4, n = t & 15;
    sB[l][n] = xdbl[(size_t)(c * CL + l) * NXD + RDT + n];
  }
  __syncthreads();
  float ac[NST];
#pragma unroll
  for (int i = 0; i < 4; ++i) {
    float4 v = *(const float4*)&Alog[(size_t)d * NST + i * 4];
    ac[i * 4 + 0] = -__expf(v.x); ac[i * 4 + 1] = -__expf(v.y);
    ac[i * 4 + 2] = -__expf(v.z); ac[i * 4 + 3] = -__expf(v.w);
  }
  float h[NST] = {};
  float dtsum = 0.f;
#pragma unroll
  for (int l = 0; l < CL; ++l) {
    float dtv = dtf[(size_t)(c * CL + l) * DINs + d];
    float xcv = xc[(size_t)(c * CL + l) * DINs + d];
    dtsum += dtv;
    float dx = dtv * xcv;
#pragma unroll
    for (int n = 0; n < NST; ++n) {
      float ab = __expf(dtv * ac[n]);
      h[n] = ab * h[n] + dx * sB[l][n];
    }
  }
  size_t base = (size_t)c * NSTATE + (size_t)d * NST;
#pragma unroll
  for (int n = 0; n < NST; ++n) {
    hout[base + n] = h[n];
    aprod[base + n] = __expf(dtsum * ac[n]);
  }
}

// ---------------- Pass B: combine chunk summaries; aprod becomes hpref in-place ----------------
__global__ __launch_bounds__(256) void k_scanB(
    float* __restrict__ aprod, const float* __restrict__ hout) {
  int s = blockIdx.x * 256 + threadIdx.x;
  float h = 0.f;
#pragma unroll 8
  for (int c = 0; c < NC; ++c) {
    size_t idx = (size_t)c * NSTATE + s;
    float a = aprod[idx];
    float b = hout[idx];
    aprod[idx] = h;
    h = a * h + b;
  }
}

// ---------------- Pass C: recompute with true h_in, fuse y + D*xc + silu(z) gate ----------------
__global__ __launch_bounds__(256) void k_scanC(
    const float* __restrict__ dtf, const float* __restrict__ xdbl,
    const float* __restrict__ xc, const float* __restrict__ xz,
    const float* __restrict__ Alog, const float* __restrict__ Dp,
    const float* __restrict__ hpref, u16* __restrict__ ybar) {
  __shared__ float sB[CL][NST], sC[CL][NST];
  const int t = threadIdx.x;
  const int d = blockIdx.x * 256 + t;
  const int c = blockIdx.y;
  {
    int l = t >> 4, n = t & 15;
    sB[l][n] = xdbl[(size_t)(c * CL + l) * NXD + RDT + n];
    sC[l][n] = xdbl[(size_t)(c * CL + l) * NXD + RDT + NST + n];
  }
  __syncthreads();
  float ac[NST];
#pragma unroll
  for (int i = 0; i < 4; ++i) {
    float4 v = *(const float4*)&Alog[(size_t)d * NST + i * 4];
    ac[i * 4 + 0] = -__expf(v.x); ac[i * 4 + 1] = -__expf(v.y);
    ac[i * 4 + 2] = -__expf(v.z); ac[i * 4 + 3] = -__expf(v.w);
  }
  float h[NST];
  size_t base = (size_t)c * NSTATE + (size_t)d * NST;
#pragma unroll
  for (int i = 0; i < 4; ++i)
    *(float4*)&h[i * 4] = *(const float4*)&hpref[base + i * 4];
  const float Dv = Dp[d];
#pragma unroll
  for (int l = 0; l < CL; ++l) {
    float dtv = dtf[(size_t)(c * CL + l) * DINs + d];
    float xcv = xc[(size_t)(c * CL + l) * DINs + d];
    float zv  = xz[(size_t)(c * CL + l) * (2 * DINs) + DINs + d];
    float dx = dtv * xcv;
    float y0 = Dv * xcv, y1 = 0.f, y2 = 0.f, y3 = 0.f;
#pragma unroll
    for (int n = 0; n < NST; n += 4) {
      float ab0 = __expf(dtv * ac[n]);
      float ab1 = __expf(dtv * ac[n + 1]);
      float ab2 = __expf(dtv * ac[n + 2]);
      float ab3 = __expf(dtv * ac[n + 3]);
      h[n]     = ab0 * h[n]     + dx * sB[l][n];
      h[n + 1] = ab1 * h[n + 1] + dx * sB[l][n + 1];
      h[n + 2] = ab2 * h[n + 2] + dx * sB[l][n + 2];
      h[n + 3] = ab3 * h[n + 3] + dx * sB[l][n + 3];
      y0 += h[n] * sC[l][n];
      y1 += h[n + 1] * sC[l][n + 1];
      y2 += h[n + 2] * sC[l][n + 2];
      y3 += h[n + 3] * sC[l][n + 3];
    }
    float y = (y0 + y1) + (y2 + y3);
    float sz = zv / (1.f + __expf(-zv));
    ybar[(size_t)(c * CL + l) * DINs + d] = f2bf(y * sz);
  }
}

// ---------------- launch ----------------
extern "C" void kernel_launch(void* const* d_in, const int* in_sizes, int n_in,
                              void* d_out, int out_size, void* d_ws, size_t ws_size,
                              hipStream_t stream) {
  (void)in_sizes; (void)n_in; (void)out_size; (void)ws_size;
  const float* x      = (const float*)d_in[0];
  const float* W_in   = (const float*)d_in[1];
  const float* conv_w = (const float*)d_in[2];
  const float* conv_b = (const float*)d_in[3];
  const float* W_x    = (const float*)d_in[4];
  const float* W_dt   = (const float*)d_in[5];
  const float* b_dt   = (const float*)d_in[6];
  const float* A_log  = (const float*)d_in[7];
  const float* D_par  = (const float*)d_in[8];
  const float* W_out  = (const float*)d_in[9];
  float* out = (float*)d_out;

  const size_t MB = 1u << 20;
  char* wsb = (char*)d_ws;
  u16*   x_bf    = (u16*)(wsb + 0);          // 2 MB   (dead after GEMM1)
  u16*   win_bf  = (u16*)(wsb + 2 * MB);     // 8 MB   (dead after GEMM1)
  u16*   a2      = (u16*)(wsb + 0);          // 12 MB  (written by conv, AFTER GEMM1)
  u16*   wout_bf = (u16*)(wsb + 12 * MB);    // 4 MB
  float* xz      = (float*)(wsb + 16 * MB);  // 16 MB
  float* xc      = (float*)(wsb + 32 * MB);  // 8 MB
  u16*   b2      = (u16*)(wsb + 40 * MB);    // 1.2 MB
  float* part    = (float*)(wsb + 42 * MB);  // 1.5 MB
  float* xdbl    = (float*)(wsb + 44 * MB);  // 384 KB
  float* dtf     = (float*)(wsb + 45 * MB);  // 8 MB
  u16*   ybar    = (u16*)(wsb + 53 * MB);    // 4 MB
  float* aprod   = (float*)(wsb + 57 * MB);  // 8 MB (becomes hpref)
  float* hout    = (float*)(wsb + 65 * MB);  // 8 MB -> total 73 MB

  k_cvt<<<1024, 256, 0, stream>>>(x, x_bf, (DMs * LSEQ) / 4);
  k_cvt<<<2048, 256, 0, stream>>>(W_in, win_bf, (2 * DINs * DMs) / 4);
  k_cvt<<<2048, 256, 0, stream>>>(W_out, wout_bf, (DMs * DINs) / 4);
  k_prepB<<<(NXD * DINs) / 256, 256, 0, stream>>>(W_x, b2);

  // GEMM1: xz[L][4096] = x * W_in^T
  k_gemm_lds<128, 128><<<dim3(LSEQ / 128, (2 * DINs) / 128), 256, 0, stream>>>(
      x_bf, win_bf, xz, LSEQ, 2 * DINs, DMs);

  k_conv<<<dim3(DINs / 256, LSEQ), 256, 0, stream>>>(xz, conv_w, conv_b, xc, a2);

  // GEMM2: split-bf16 MFMA, K' = 6144, K-split 4
  k_gemm2m<<<dim3(LSEQ / 64, 4), 256, 0, stream>>>(a2, b2, part);
  k_red4<<<(LSEQ * NXD) / 256, 256, 0, stream>>>(part, xdbl);

  k_gemm3<<<dim3(DINs / 256, LSEQ / 16), 256, 0, stream>>>(xdbl, W_dt, b_dt, dtf);

  // chunked scan
  k_scanA<<<dim3(DINs / 256, NC), 256, 0, stream>>>(dtf, xdbl, xc, A_log, aprod, hout);
  k_scanB<<<NSTATE / 256, 256, 0, stream>>>(aprod, hout);
  k_scanC<<<dim3(DINs / 256, NC), 256, 0, stream>>>(dtf, xdbl, xc, xz, A_log, D_par,
                                                    aprod, ybar);

  // GEMM4: out[L][1024] = ybar * W_out^T
  k_gemm_lds<64, 128><<<dim3(LSEQ / 64, DMs / 128), 256, 0, stream>>>(
      ybar, wout_bf, out, LSEQ, DMs, DINs);
}

// Round 4
// 136.172 us; speedup vs baseline: 3.3923x; 1.3371x over previous
//
#include <hip/hip_runtime.h>
#include <hip/hip_bf16.h>
#include <cstdint>
#include <cstddef>

typedef unsigned short u16;
typedef short bf16x8 __attribute__((ext_vector_type(8)));
typedef float f32x4 __attribute__((ext_vector_type(4)));

typedef __attribute__((address_space(1))) void gvoid;
typedef __attribute__((address_space(3))) void lvoid;

#define DMs   1024
#define DINs  2048
#define LSEQ  1024
#define NST   16
#define RDT   64
#define NXD   96   /* R + 2N */
#define CL    16   /* scan chunk length */
#define NC    64   /* number of chunks */
#define NSTATE (DINs * NST)   /* 32768 */
#define K2    6144 /* split-bf16 GEMM2 K' = 3*2048 */
#define KS2   8    /* GEMM2 K-split */

__device__ __forceinline__ u16 f2bf(float f) {
  uint32_t u = __builtin_bit_cast(uint32_t, f);
  u += 0x7FFFu + ((u >> 16) & 1u);
  return (u16)(u >> 16);
}
__device__ __forceinline__ float bf2f(u16 h) {
  return __builtin_bit_cast(float, (uint32_t)h << 16);
}
__device__ __forceinline__ void gload_lds16(const u16* g, u16* l) {
  __builtin_amdgcn_global_load_lds((gvoid*)g, (lvoid*)l, 16, 0, 0);
}

// ---------------- fused prep: cvt x/W_in/W_out to bf16, W_x to hi/lo b2 ----------------
__device__ __forceinline__ void cvt4(const float* in, u16* out, int j) {
  float4 v = reinterpret_cast<const float4*>(in)[j];
  ushort4 o;
  o.x = f2bf(v.x); o.y = f2bf(v.y); o.z = f2bf(v.z); o.w = f2bf(v.w);
  reinterpret_cast<ushort4*>(out)[j] = o;
}
__global__ __launch_bounds__(256) void k_prep(
    const float* __restrict__ x, const float* __restrict__ Win,
    const float* __restrict__ Wout, const float* __restrict__ Wx,
    u16* __restrict__ x_bf, u16* __restrict__ win_bf,
    u16* __restrict__ wout_bf, u16* __restrict__ b2) {
  int tid = blockIdx.x * 256 + threadIdx.x;
  int stride = gridDim.x * 256;
  for (int j = tid; j < (DMs * LSEQ) / 4; j += stride) cvt4(x, x_bf, j);
  for (int j = tid; j < (2 * DINs * DMs) / 4; j += stride) cvt4(Win, win_bf, j);
  for (int j = tid; j < (DMs * DINs) / 4; j += stride) cvt4(Wout, wout_bf, j);
  for (int j = tid; j < NXD * DINs; j += stride) {
    int c = j >> 11, k = j & 2047;
    float v = Wx[j];
    u16 hi = f2bf(v);
    u16 lo = f2bf(v - bf2f(hi));
    size_t base = (size_t)c * K2;
    b2[base + k] = hi;
    b2[base + DINs + k] = hi;
    b2[base + 2 * DINs + k] = lo;
  }
}

// ---------------- double-buffered MFMA GEMM (counted-vmcnt pipeline) ----------------
// C[M][N] = A[M][K] * B[N][K]^T.  Linear LDS [rows][32], BK=32, 4 waves 2x2.
template<int TM, int TN>
__global__ __launch_bounds__(256) void k_gemm_db(
    const u16* __restrict__ A, const u16* __restrict__ B, float* __restrict__ C,
    int M, int N, int K) {
  constexpr int WTM = TM / 2, WTN = TN / 2;
  constexpr int FM = WTM / 16, FN = WTN / 16;
  constexpr int LA = TM / 64, LB = TN / 64;
  __shared__ __align__(16) u16 As[2][TM * 32];
  __shared__ __align__(16) u16 Bs[2][TN * 32];
  const int t = threadIdx.x;
  const int lane = t & 63, w = t >> 6;
  const int m0 = blockIdx.x * TM, n0 = blockIdx.y * TN;
  const int wm = (w >> 1) * WTM, wn = (w & 1) * WTN;
  const int fr = lane & 15, g = lane >> 4;
  const int ar = t >> 2, acg = (t & 3) * 8;
  f32x4 acc[FM][FN] = {};
  const int nt = K / 32;
  auto stage = [&](int buf, int k0) {
#pragma unroll
    for (int i = 0; i < LA; ++i)
      gload_lds16(&A[(size_t)(m0 + ar + i * 64) * K + k0 + acg], &As[buf][(t + i * 256) * 8]);
#pragma unroll
    for (int i = 0; i < LB; ++i)
      gload_lds16(&B[(size_t)(n0 + ar + i * 64) * K + k0 + acg], &Bs[buf][(t + i * 256) * 8]);
  };
  stage(0, 0);
  int cur = 0;
  for (int tt = 0; tt < nt; ++tt) {
    if (tt + 1 < nt) {
      stage(cur ^ 1, (tt + 1) * 32);
      asm volatile("s_waitcnt vmcnt(%0)" :: "n"(LA + LB) : "memory");
    } else {
      asm volatile("s_waitcnt vmcnt(0)" ::: "memory");
    }
    __builtin_amdgcn_s_barrier();
    bf16x8 af[FM], bfv[FN];
#pragma unroll
    for (int i = 0; i < FM; ++i)
      af[i] = *(const bf16x8*)&As[cur][(wm + i * 16 + fr) * 32 + g * 8];
#pragma unroll
    for (int j = 0; j < FN; ++j)
      bfv[j] = *(const bf16x8*)&Bs[cur][(wn + j * 16 + fr) * 32 + g * 8];
#pragma unroll
    for (int i = 0; i < FM; ++i)
#pragma unroll
      for (int j = 0; j < FN; ++j)
        acc[i][j] = __builtin_amdgcn_mfma_f32_16x16x32_bf16(af[i], bfv[j], acc[i][j], 0, 0, 0);
    __builtin_amdgcn_s_barrier();
    cur ^= 1;
  }
  // C/D layout: col = lane&15, row = (lane>>4)*4 + reg
#pragma unroll
  for (int i = 0; i < FM; ++i)
#pragma unroll
    for (int j = 0; j < FN; ++j) {
      int mb = m0 + wm + i * 16 + g * 4;
      int nn = n0 + wn + j * 16 + fr;
#pragma unroll
      for (int e = 0; e < 4; ++e)
        C[(size_t)(mb + e) * N + nn] = acc[i][j][e];
    }
}

// ---------------- causal depthwise conv (K=4) + bias + silu; emits xc f32 and A2 hi/lo/hi bf16 ----------------
__global__ __launch_bounds__(256) void k_conv(
    const float* __restrict__ xz, const float* __restrict__ cw, const float* __restrict__ cb,
    float* __restrict__ xc, u16* __restrict__ a2) {
  int d = blockIdx.x * 256 + threadIdx.x;
  int l = blockIdx.y;
  float4 wv = *(const float4*)&cw[d * 4];
  float acc = cb[d];
  const float wj[4] = {wv.x, wv.y, wv.z, wv.w};
#pragma unroll
  for (int j = 0; j < 4; ++j) {
    int ls = l - 3 + j;
    if (ls >= 0) acc += wj[j] * xz[(size_t)ls * (2 * DINs) + d];
  }
  float sg = 1.f / (1.f + __expf(-acc));
  float v = acc * sg;
  xc[(size_t)l * DINs + d] = v;
  u16 hi = f2bf(v);
  u16 lo = f2bf(v - bf2f(hi));
  size_t base = (size_t)l * K2;
  a2[base + d] = hi;
  a2[base + DINs + d] = lo;
  a2[base + 2 * DINs + d] = hi;
}

// ---------------- GEMM2 (split-bf16 MFMA, dbuf, K-split 8): part[ks][L][96] ----------------
// Stages 128 B-rows (rows 96..127 are harmless garbage within the 2MB b2 slot).
__global__ __launch_bounds__(256) void k_gemm2db(
    const u16* __restrict__ A2, const u16* __restrict__ B2, float* __restrict__ part) {
  __shared__ __align__(16) u16 As[2][64 * 32];
  __shared__ __align__(16) u16 Bs[2][128 * 32];
  const int t = threadIdx.x;
  const int lane = t & 63, w = t >> 6;
  const int m0 = blockIdx.x * 64;
  const int ks = blockIdx.y;
  const int kbeg = ks * (K2 / KS2);
  const int wm = (w >> 1) * 32, wn = (w & 1) * 48;
  const int fr = lane & 15, g = lane >> 4;
  const int ar = t >> 2, acg = (t & 3) * 8;
  f32x4 acc[2][3] = {};
  const int nt = (K2 / KS2) / 32;   // 24
  auto stage = [&](int buf, int k0) {
    gload_lds16(&A2[(size_t)(m0 + ar) * K2 + k0 + acg], &As[buf][t * 8]);
#pragma unroll
    for (int i = 0; i < 2; ++i)
      gload_lds16(&B2[(size_t)(ar + i * 64) * K2 + k0 + acg], &Bs[buf][(t + i * 256) * 8]);
  };
  stage(0, kbeg);
  int cur = 0;
  for (int tt = 0; tt < nt; ++tt) {
    if (tt + 1 < nt) {
      stage(cur ^ 1, kbeg + (tt + 1) * 32);
      asm volatile("s_waitcnt vmcnt(3)" ::: "memory");
    } else {
      asm volatile("s_waitcnt vmcnt(0)" ::: "memory");
    }
    __builtin_amdgcn_s_barrier();
    bf16x8 af[2], bfv[3];
#pragma unroll
    for (int i = 0; i < 2; ++i)
      af[i] = *(const bf16x8*)&As[cur][(wm + i * 16 + fr) * 32 + g * 8];
#pragma unroll
    for (int j = 0; j < 3; ++j)
      bfv[j] = *(const bf16x8*)&Bs[cur][(wn + j * 16 + fr) * 32 + g * 8];
#pragma unroll
    for (int i = 0; i < 2; ++i)
#pragma unroll
      for (int j = 0; j < 3; ++j)
        acc[i][j] = __builtin_amdgcn_mfma_f32_16x16x32_bf16(af[i], bfv[j], acc[i][j], 0, 0, 0);
    __builtin_amdgcn_s_barrier();
    cur ^= 1;
  }
  float* P = part + (size_t)ks * (LSEQ * NXD);
#pragma unroll
  for (int i = 0; i < 2; ++i)
#pragma unroll
    for (int j = 0; j < 3; ++j) {
      int mb = m0 + wm + i * 16 + g * 4;
      int nn = wn + j * 16 + fr;
#pragma unroll
      for (int e = 0; e < 4; ++e)
        P[(size_t)(mb + e) * NXD + nn] = acc[i][j][e];
    }
}

__global__ void k_red8(const float* __restrict__ part, float* __restrict__ xdbl) {
  int i = blockIdx.x * 256 + threadIdx.x;
  const int S = LSEQ * NXD;
  float s = 0.f;
#pragma unroll
  for (int k = 0; k < KS2; ++k) s += part[i + (size_t)k * S];
  xdbl[i] = s;
}

// ---------------- GEMM3: dt[L][2048] = softplus(x_dbl[:, :64] * W_dt^T + b_dt) ----------------
__global__ __launch_bounds__(256) void k_gemm3(
    const float* __restrict__ xdbl, const float* __restrict__ Wdt,
    const float* __restrict__ bdt, float* __restrict__ dtf) {
  int d = blockIdx.x * 256 + threadIdx.x;
  int r0 = blockIdx.y * 16;
  float wreg[64];
#pragma unroll
  for (int i = 0; i < 16; ++i)
    *(float4*)&wreg[i * 4] = *(const float4*)&Wdt[(size_t)d * RDT + i * 4];
  float bv = bdt[d];
  for (int r = r0; r < r0 + 16; ++r) {
    const float* xrow = xdbl + (size_t)r * NXD;
    float acc = bv;
#pragma unroll
    for (int i = 0; i < 16; ++i) {
      float4 xv = *(const float4*)&xrow[i * 4];
      acc += xv.x * wreg[i * 4] + xv.y * wreg[i * 4 + 1] + xv.z * wreg[i * 4 + 2] + xv.w * wreg[i * 4 + 3];
    }
    float sp = acc > 20.f ? acc : logf(1.f + __expf(acc));
    dtf[(size_t)r * DINs + d] = sp;
  }
}

// ---------------- Pass A: chunk-local scan (h_in = 0) + chunk A-product ----------------
__global__ __launch_bounds__(256) void k_scanA(
    const float* __restrict__ dtf, const float* __restrict__ xdbl,
    const float* __restrict__ xc, const float* __restrict__ Alog,
    float* __restrict__ aprod, float* __restrict__ hout) {
  __shared__ float sB[CL][NST];
  const int t = threadIdx.x;
  const int d = blockIdx.x * 256 + t;
  const int c = blockIdx.y;
  {
    int l = t >> 4, n = t & 15;
    sB[l][n] = xdbl[(size_t)(c * CL + l) * NXD + RDT + n];
  }
  __syncthreads();
  float ac[NST];
#pragma unroll
  for (int i = 0; i < 4; ++i) {
    float4 v = *(const float4*)&Alog[(size_t)d * NST + i * 4];
    ac[i * 4 + 0] = -__expf(v.x); ac[i * 4 + 1] = -__expf(v.y);
    ac[i * 4 + 2] = -__expf(v.z); ac[i * 4 + 3] = -__expf(v.w);
  }
  float h[NST] = {};
  float dtsum = 0.f;
#pragma unroll
  for (int l = 0; l < CL; ++l) {
    float dtv = dtf[(size_t)(c * CL + l) * DINs + d];
    float xcv = xc[(size_t)(c * CL + l) * DINs + d];
    dtsum += dtv;
    float dx = dtv * xcv;
#pragma unroll
    for (int n = 0; n < NST; ++n) {
      float ab = __expf(dtv * ac[n]);
      h[n] = ab * h[n] + dx * sB[l][n];
    }
  }
  size_t base = (size_t)c * NSTATE + (size_t)d * NST;
#pragma unroll
  for (int n = 0; n < NST; ++n) {
    hout[base + n] = h[n];
    aprod[base + n] = __expf(dtsum * ac[n]);
  }
}

// ---------------- Pass B: combine chunk summaries; aprod becomes hpref in-place ----------------
__global__ __launch_bounds__(256) void k_scanB(
    float* __restrict__ aprod, const float* __restrict__ hout) {
  int s = blockIdx.x * 256 + threadIdx.x;
  float h = 0.f;
#pragma unroll 8
  for (int c = 0; c < NC; ++c) {
    size_t idx = (size_t)c * NSTATE + s;
    float a = aprod[idx];
    float b = hout[idx];
    aprod[idx] = h;
    h = a * h + b;
  }
}

// ---------------- Pass C: recompute with true h_in, fuse y + D*xc + silu(z) gate ----------------
__global__ __launch_bounds__(256) void k_scanC(
    const float* __restrict__ dtf, const float* __restrict__ xdbl,
    const float* __restrict__ xc, const float* __restrict__ xz,
    const float* __restrict__ Alog, const float* __restrict__ Dp,
    const float* __restrict__ hpref, u16* __restrict__ ybar) {
  __shared__ float sB[CL][NST], sC[CL][NST];
  const int t = threadIdx.x;
  const int d = blockIdx.x * 256 + t;
  const int c = blockIdx.y;
  {
    int l = t >> 4, n = t & 15;
    sB[l][n] = xdbl[(size_t)(c * CL + l) * NXD + RDT + n];
    sC[l][n] = xdbl[(size_t)(c * CL + l) * NXD + RDT + NST + n];
  }
  __syncthreads();
  float ac[NST];
#pragma unroll
  for (int i = 0; i < 4; ++i) {
    float4 v = *(const float4*)&Alog[(size_t)d * NST + i * 4];
    ac[i * 4 + 0] = -__expf(v.x); ac[i * 4 + 1] = -__expf(v.y);
    ac[i * 4 + 2] = -__expf(v.z); ac[i * 4 + 3] = -__expf(v.w);
  }
  float h[NST];
  size_t base = (size_t)c * NSTATE + (size_t)d * NST;
#pragma unroll
  for (int i = 0; i < 4; ++i)
    *(float4*)&h[i * 4] = *(const float4*)&hpref[base + i * 4];
  const float Dv = Dp[d];
#pragma unroll
  for (int l = 0; l < CL; ++l) {
    float dtv = dtf[(size_t)(c * CL + l) * DINs + d];
    float xcv = xc[(size_t)(c * CL + l) * DINs + d];
    float zv  = xz[(size_t)(c * CL + l) * (2 * DINs) + DINs + d];
    float dx = dtv * xcv;
    float y0 = Dv * xcv, y1 = 0.f, y2 = 0.f, y3 = 0.f;
#pragma unroll
    for (int n = 0; n < NST; n += 4) {
      float ab0 = __expf(dtv * ac[n]);
      float ab1 = __expf(dtv * ac[n + 1]);
      float ab2 = __expf(dtv * ac[n + 2]);
      float ab3 = __expf(dtv * ac[n + 3]);
      h[n]     = ab0 * h[n]     + dx * sB[l][n];
      h[n + 1] = ab1 * h[n + 1] + dx * sB[l][n + 1];
      h[n + 2] = ab2 * h[n + 2] + dx * sB[l][n + 2];
      h[n + 3] = ab3 * h[n + 3] + dx * sB[l][n + 3];
      y0 += h[n] * sC[l][n];
      y1 += h[n + 1] * sC[l][n + 1];
      y2 += h[n + 2] * sC[l][n + 2];
      y3 += h[n + 3] * sC[l][n + 3];
    }
    float y = (y0 + y1) + (y2 + y3);
    float sz = zv / (1.f + __expf(-zv));
    ybar[(size_t)(c * CL + l) * DINs + d] = f2bf(y * sz);
  }
}

// ---------------- launch ----------------
extern "C" void kernel_launch(void* const* d_in, const int* in_sizes, int n_in,
                              void* d_out, int out_size, void* d_ws, size_t ws_size,
                              hipStream_t stream) {
  (void)in_sizes; (void)n_in; (void)out_size; (void)ws_size;
  const float* x      = (const float*)d_in[0];
  const float* W_in   = (const float*)d_in[1];
  const float* conv_w = (const float*)d_in[2];
  const float* conv_b = (const float*)d_in[3];
  const float* W_x    = (const float*)d_in[4];
  const float* W_dt   = (const float*)d_in[5];
  const float* b_dt   = (const float*)d_in[6];
  const float* A_log  = (const float*)d_in[7];
  const float* D_par  = (const float*)d_in[8];
  const float* W_out  = (const float*)d_in[9];
  float* out = (float*)d_out;

  const size_t MB = 1u << 20;
  char* wsb = (char*)d_ws;
  u16*   x_bf    = (u16*)(wsb + 0);          // 2 MB   (dead after GEMM1)
  u16*   win_bf  = (u16*)(wsb + 2 * MB);     // 8 MB   (dead after GEMM1)
  u16*   a2      = (u16*)(wsb + 0);          // 12 MB  (written by conv, AFTER GEMM1)
  u16*   wout_bf = (u16*)(wsb + 12 * MB);    // 4 MB
  float* xz      = (float*)(wsb + 16 * MB);  // 16 MB
  float* xc      = (float*)(wsb + 32 * MB);  // 8 MB
  u16*   b2      = (u16*)(wsb + 40 * MB);    // 1.2 MB (2 MB slot; over-read OK)
  float* part    = (float*)(wsb + 42 * MB);  // 3 MB
  float* xdbl    = (float*)(wsb + 45 * MB);  // 384 KB
  float* dtf     = (float*)(wsb + 46 * MB);  // 8 MB
  u16*   ybar    = (u16*)(wsb + 54 * MB);    // 4 MB
  float* aprod   = (float*)(wsb + 58 * MB);  // 8 MB (becomes hpref)
  float* hout    = (float*)(wsb + 66 * MB);  // 8 MB -> total 74 MB

  k_prep<<<1024, 256, 0, stream>>>(x, W_in, W_out, W_x, x_bf, win_bf, wout_bf, b2);

  // GEMM1: xz[L][4096] = x * W_in^T   (grid 16x32 = 512 blocks)
  k_gemm_db<64, 128><<<dim3(LSEQ / 64, (2 * DINs) / 128), 256, 0, stream>>>(
      x_bf, win_bf, xz, LSEQ, 2 * DINs, DMs);

  k_conv<<<dim3(DINs / 256, LSEQ), 256, 0, stream>>>(xz, conv_w, conv_b, xc, a2);

  // GEMM2: split-bf16 MFMA, K' = 6144, K-split 8 (grid 16x8 = 128 blocks)
  k_gemm2db<<<dim3(LSEQ / 64, KS2), 256, 0, stream>>>(a2, b2, part);
  k_red8<<<(LSEQ * NXD) / 256, 256, 0, stream>>>(part, xdbl);

  k_gemm3<<<dim3(DINs / 256, LSEQ / 16), 256, 0, stream>>>(xdbl, W_dt, b_dt, dtf);

  // chunked scan
  k_scanA<<<dim3(DINs / 256, NC), 256, 0, stream>>>(dtf, xdbl, xc, A_log, aprod, hout);
  k_scanB<<<NSTATE / 256, 256, 0, stream>>>(aprod, hout);
  k_scanC<<<dim3(DINs / 256, NC), 256, 0, stream>>>(dtf, xdbl, xc, xz, A_log, D_par,
                                                    aprod, ybar);

  // GEMM4: out[L][1024] = ybar * W_out^T   (grid 16x16 = 256 blocks)
  k_gemm_db<64, 64><<<dim3(LSEQ / 64, DMs / 64), 256, 0, stream>>>(
      ybar, wout_bf, out, LSEQ, DMs, DINs);
}

// Round 5
// 118.775 us; speedup vs baseline: 3.8891x; 1.1465x over previous
//
#include <hip/hip_runtime.h>
#include <hip/hip_bf16.h>
#include <cstdint>
#include <cstddef>

typedef unsigned short u16;
typedef short bf16x8 __attribute__((ext_vector_type(8)));
typedef float f32x4 __attribute__((ext_vector_type(4)));

typedef __attribute__((address_space(1))) void gvoid;
typedef __attribute__((address_space(3))) void lvoid;

#define DMs   1024
#define DINs  2048
#define LSEQ  1024
#define NST   16
#define RDT   64
#define NXD   96   /* R + 2N */
#define CL    16   /* scan chunk length */
#define NC    64   /* number of chunks */
#define NSTATE (DINs * NST)   /* 32768 */
#define K2    6144 /* split-bf16 GEMM2 K' = 3*2048 */
#define KS2   8    /* GEMM2 K-split */

__device__ __forceinline__ u16 f2bf(float f) {
  uint32_t u = __builtin_bit_cast(uint32_t, f);
  u += 0x7FFFu + ((u >> 16) & 1u);
  return (u16)(u >> 16);
}
__device__ __forceinline__ float bf2f(u16 h) {
  return __builtin_bit_cast(float, (uint32_t)h << 16);
}
__device__ __forceinline__ void gload_lds16(const u16* g, u16* l) {
  __builtin_amdgcn_global_load_lds((gvoid*)g, (lvoid*)l, 16, 0, 0);
}

// ---------------- fused prep: cvt x/W_in/W_out to bf16, W_x to hi/lo b2 ----------------
__device__ __forceinline__ void cvt4(const float* in, u16* out, int j) {
  float4 v = reinterpret_cast<const float4*>(in)[j];
  ushort4 o;
  o.x = f2bf(v.x); o.y = f2bf(v.y); o.z = f2bf(v.z); o.w = f2bf(v.w);
  reinterpret_cast<ushort4*>(out)[j] = o;
}
__global__ __launch_bounds__(256) void k_prep(
    const float* __restrict__ x, const float* __restrict__ Win,
    const float* __restrict__ Wout, const float* __restrict__ Wx,
    u16* __restrict__ x_bf, u16* __restrict__ win_bf,
    u16* __restrict__ wout_bf, u16* __restrict__ b2) {
  int tid = blockIdx.x * 256 + threadIdx.x;
  int stride = gridDim.x * 256;
  for (int j = tid; j < (DMs * LSEQ) / 4; j += stride) cvt4(x, x_bf, j);
  for (int j = tid; j < (2 * DINs * DMs) / 4; j += stride) cvt4(Win, win_bf, j);
  for (int j = tid; j < (DMs * DINs) / 4; j += stride) cvt4(Wout, wout_bf, j);
  for (int j = tid; j < NXD * DINs; j += stride) {
    int c = j >> 11, k = j & 2047;
    float v = Wx[j];
    u16 hi = f2bf(v);
    u16 lo = f2bf(v - bf2f(hi));
    size_t base = (size_t)c * K2;
    b2[base + k] = hi;
    b2[base + DINs + k] = hi;
    b2[base + 2 * DINs + k] = lo;
  }
}

// ---------------- double-buffered MFMA GEMM, BK=64, counted vmcnt, optional K-split ----------------
// C[ksp][M][N] = A[M][kslice] * B[N][kslice]^T.  Linear LDS [rows][BK], 4 waves 2x2.
template<int TM, int TN, int BK, int KSPLIT>
__global__ __launch_bounds__(256) void k_gemm_db(
    const u16* __restrict__ A, const u16* __restrict__ B, float* __restrict__ C,
    int M, int N, int K) {
  constexpr int WTM = TM / 2, WTN = TN / 2;
  constexpr int FM = WTM / 16, FN = WTN / 16;
  constexpr int KSUB = BK / 32;
  constexpr int LA = TM * BK / 2048, LB = TN * BK / 2048;
  constexpr int TPR = BK / 8;       // threads per staged row
  constexpr int RPR = 256 / TPR;    // rows per staging round
  __shared__ __align__(16) u16 As[2][TM * BK];
  __shared__ __align__(16) u16 Bs[2][TN * BK];
  const int t = threadIdx.x;
  const int lane = t & 63, w = t >> 6;
  const int m0 = blockIdx.x * TM, n0 = blockIdx.y * TN;
  const int kbase = blockIdx.z * (K / KSPLIT);
  const int wm = (w >> 1) * WTM, wn = (w & 1) * WTN;
  const int fr = lane & 15, g = lane >> 4;
  const int ar = t / TPR, acg = (t % TPR) * 8;
  f32x4 acc[FM][FN] = {};
  const int nt = (K / KSPLIT) / BK;
  auto stage = [&](int buf, int k0) {
#pragma unroll
    for (int i = 0; i < LA; ++i)
      gload_lds16(&A[(size_t)(m0 + ar + i * RPR) * K + k0 + acg], &As[buf][(t + i * 256) * 8]);
#pragma unroll
    for (int i = 0; i < LB; ++i)
      gload_lds16(&B[(size_t)(n0 + ar + i * RPR) * K + k0 + acg], &Bs[buf][(t + i * 256) * 8]);
  };
  stage(0, kbase);
  int cur = 0;
  for (int tt = 0; tt < nt; ++tt) {
    if (tt + 1 < nt) {
      stage(cur ^ 1, kbase + (tt + 1) * BK);
      asm volatile("s_waitcnt vmcnt(%0)" :: "n"(LA + LB) : "memory");
    } else {
      asm volatile("s_waitcnt vmcnt(0)" ::: "memory");
    }
    __builtin_amdgcn_s_barrier();
    bf16x8 af[FM][KSUB], bfv[FN][KSUB];
#pragma unroll
    for (int i = 0; i < FM; ++i)
#pragma unroll
      for (int ks = 0; ks < KSUB; ++ks)
        af[i][ks] = *(const bf16x8*)&As[cur][(wm + i * 16 + fr) * BK + ks * 32 + g * 8];
#pragma unroll
    for (int j = 0; j < FN; ++j)
#pragma unroll
      for (int ks = 0; ks < KSUB; ++ks)
        bfv[j][ks] = *(const bf16x8*)&Bs[cur][(wn + j * 16 + fr) * BK + ks * 32 + g * 8];
#pragma unroll
    for (int ks = 0; ks < KSUB; ++ks)
#pragma unroll
      for (int i = 0; i < FM; ++i)
#pragma unroll
        for (int j = 0; j < FN; ++j)
          acc[i][j] = __builtin_amdgcn_mfma_f32_16x16x32_bf16(af[i][ks], bfv[j][ks], acc[i][j], 0, 0, 0);
    __builtin_amdgcn_s_barrier();
    cur ^= 1;
  }
  float* Co = C + (size_t)blockIdx.z * M * N;
  // C/D layout: col = lane&15, row = (lane>>4)*4 + reg
#pragma unroll
  for (int i = 0; i < FM; ++i)
#pragma unroll
    for (int j = 0; j < FN; ++j) {
      int mb = m0 + wm + i * 16 + g * 4;
      int nn = n0 + wn + j * 16 + fr;
#pragma unroll
      for (int e = 0; e < 4; ++e)
        Co[(size_t)(mb + e) * N + nn] = acc[i][j][e];
    }
}

// out = p0 + p1 (GEMM4 K-split reduce)
__global__ void k_add2(const float* __restrict__ p, float* __restrict__ out, int n4) {
  int j = blockIdx.x * 256 + threadIdx.x;
  if (j < n4) {
    float4 a = reinterpret_cast<const float4*>(p)[j];
    float4 b = reinterpret_cast<const float4*>(p + (size_t)DMs * LSEQ)[j];
    float4 o; o.x = a.x + b.x; o.y = a.y + b.y; o.z = a.z + b.z; o.w = a.w + b.w;
    reinterpret_cast<float4*>(out)[j] = o;
  }
}

// ---------------- causal depthwise conv (K=4) + bias + silu; 16 l per thread ----------------
__global__ __launch_bounds__(256) void k_conv(
    const float* __restrict__ xz, const float* __restrict__ cw, const float* __restrict__ cb,
    float* __restrict__ xc, u16* __restrict__ a2) {
  int d = blockIdx.x * 256 + threadIdx.x;
  int l0 = blockIdx.y * 16;
  float4 wv = *(const float4*)&cw[d * 4];
  float bias = cb[d];
  float xm3 = l0 >= 3 ? xz[(size_t)(l0 - 3) * (2 * DINs) + d] : 0.f;
  float xm2 = l0 >= 2 ? xz[(size_t)(l0 - 2) * (2 * DINs) + d] : 0.f;
  float xm1 = l0 >= 1 ? xz[(size_t)(l0 - 1) * (2 * DINs) + d] : 0.f;
#pragma unroll
  for (int li = 0; li < 16; ++li) {
    int l = l0 + li;
    float xcur = xz[(size_t)l * (2 * DINs) + d];
    float acc = bias + wv.x * xm3 + wv.y * xm2 + wv.z * xm1 + wv.w * xcur;
    float sg = 1.f / (1.f + __expf(-acc));
    float v = acc * sg;
    xc[(size_t)l * DINs + d] = v;
    u16 hi = f2bf(v);
    u16 lo = f2bf(v - bf2f(hi));
    size_t base = (size_t)l * K2;
    a2[base + d] = hi;
    a2[base + DINs + d] = lo;
    a2[base + 2 * DINs + d] = hi;
    xm3 = xm2; xm2 = xm1; xm1 = xcur;
  }
}

// ---------------- GEMM2 (split-bf16 MFMA, dbuf, BK=64, K-split 8): part[ks][L][96] ----------------
__global__ __launch_bounds__(256) void k_gemm2db(
    const u16* __restrict__ A2, const u16* __restrict__ B2, float* __restrict__ part) {
  __shared__ __align__(16) u16 As[2][64 * 64];
  __shared__ __align__(16) u16 Bs[2][96 * 64];
  const int t = threadIdx.x;
  const int lane = t & 63, w = t >> 6;
  const int m0 = blockIdx.x * 64;
  const int ks = blockIdx.y;
  const int kbeg = ks * (K2 / KS2);
  const int wm = (w >> 1) * 32, wn = (w & 1) * 48;
  const int fr = lane & 15, g = lane >> 4;
  const int ar = t >> 3, acg = (t & 7) * 8;
  f32x4 acc[2][3] = {};
  const int nt = (K2 / KS2) / 64;   // 12
  auto stage = [&](int buf, int k0) {
#pragma unroll
    for (int i = 0; i < 2; ++i)
      gload_lds16(&A2[(size_t)(m0 + ar + i * 32) * K2 + k0 + acg], &As[buf][(t + i * 256) * 8]);
#pragma unroll
    for (int i = 0; i < 3; ++i)
      gload_lds16(&B2[(size_t)(ar + i * 32) * K2 + k0 + acg], &Bs[buf][(t + i * 256) * 8]);
  };
  stage(0, kbeg);
  int cur = 0;
  for (int tt = 0; tt < nt; ++tt) {
    if (tt + 1 < nt) {
      stage(cur ^ 1, kbeg + (tt + 1) * 64);
      asm volatile("s_waitcnt vmcnt(5)" ::: "memory");
    } else {
      asm volatile("s_waitcnt vmcnt(0)" ::: "memory");
    }
    __builtin_amdgcn_s_barrier();
    bf16x8 af[2][2], bfv[3][2];
#pragma unroll
    for (int i = 0; i < 2; ++i)
#pragma unroll
      for (int kk = 0; kk < 2; ++kk)
        af[i][kk] = *(const bf16x8*)&As[cur][(wm + i * 16 + fr) * 64 + kk * 32 + g * 8];
#pragma unroll
    for (int j = 0; j < 3; ++j)
#pragma unroll
      for (int kk = 0; kk < 2; ++kk)
        bfv[j][kk] = *(const bf16x8*)&Bs[cur][(wn + j * 16 + fr) * 64 + kk * 32 + g * 8];
#pragma unroll
    for (int kk = 0; kk < 2; ++kk)
#pragma unroll
      for (int i = 0; i < 2; ++i)
#pragma unroll
        for (int j = 0; j < 3; ++j)
          acc[i][j] = __builtin_amdgcn_mfma_f32_16x16x32_bf16(af[i][kk], bfv[j][kk], acc[i][j], 0, 0, 0);
    __builtin_amdgcn_s_barrier();
    cur ^= 1;
  }
  float* P = part + (size_t)ks * (LSEQ * NXD);
#pragma unroll
  for (int i = 0; i < 2; ++i)
#pragma unroll
    for (int j = 0; j < 3; ++j) {
      int mb = m0 + wm + i * 16 + g * 4;
      int nn = wn + j * 16 + fr;
#pragma unroll
      for (int e = 0; e < 4; ++e)
        P[(size_t)(mb + e) * NXD + nn] = acc[i][j][e];
    }
}

__global__ void k_red8(const float* __restrict__ part, float* __restrict__ xdbl) {
  int i = blockIdx.x * 256 + threadIdx.x;
  const int S = LSEQ * NXD;
  float s = 0.f;
#pragma unroll
  for (int k = 0; k < KS2; ++k) s += part[i + (size_t)k * S];
  xdbl[i] = s;
}

// ---------------- GEMM3: dt[L][2048] = softplus(x_dbl[:, :64] * W_dt^T + b_dt) ----------------
__global__ __launch_bounds__(256) void k_gemm3(
    const float* __restrict__ xdbl, const float* __restrict__ Wdt,
    const float* __restrict__ bdt, float* __restrict__ dtf) {
  int d = blockIdx.x * 256 + threadIdx.x;
  int r0 = blockIdx.y * 16;
  float wreg[64];
#pragma unroll
  for (int i = 0; i < 16; ++i)
    *(float4*)&wreg[i * 4] = *(const float4*)&Wdt[(size_t)d * RDT + i * 4];
  float bv = bdt[d];
  for (int r = r0; r < r0 + 16; ++r) {
    const float* xrow = xdbl + (size_t)r * NXD;
    float acc = bv;
#pragma unroll
    for (int i = 0; i < 16; ++i) {
      float4 xv = *(const float4*)&xrow[i * 4];
      acc += xv.x * wreg[i * 4] + xv.y * wreg[i * 4 + 1] + xv.z * wreg[i * 4 + 2] + xv.w * wreg[i * 4 + 3];
    }
    float sp = acc > 20.f ? acc : logf(1.f + __expf(acc));
    dtf[(size_t)r * DINs + d] = sp;
  }
}

// ---------------- Pass A: chunk-local scan (h_in = 0); emits hout + dtsum ----------------
__global__ __launch_bounds__(256) void k_scanA(
    const float* __restrict__ dtf, const float* __restrict__ xdbl,
    const float* __restrict__ xc, const float* __restrict__ Alog,
    float* __restrict__ hout, float* __restrict__ dts) {
  __shared__ float sB[CL][NST];
  const int t = threadIdx.x;
  const int d = blockIdx.x * 256 + t;
  const int c = blockIdx.y;
  {
    int l = t >> 4, n = t & 15;
    sB[l][n] = xdbl[(size_t)(c * CL + l) * NXD + RDT + n];
  }
  __syncthreads();
  float ac[NST];
#pragma unroll
  for (int i = 0; i < 4; ++i) {
    float4 v = *(const float4*)&Alog[(size_t)d * NST + i * 4];
    ac[i * 4 + 0] = -__expf(v.x); ac[i * 4 + 1] = -__expf(v.y);
    ac[i * 4 + 2] = -__expf(v.z); ac[i * 4 + 3] = -__expf(v.w);
  }
  float h[NST] = {};
  float dtsum = 0.f;
#pragma unroll
  for (int l = 0; l < CL; ++l) {
    float dtv = dtf[(size_t)(c * CL + l) * DINs + d];
    float xcv = xc[(size_t)(c * CL + l) * DINs + d];
    dtsum += dtv;
    float dx = dtv * xcv;
#pragma unroll
    for (int n = 0; n < NST; ++n) {
      float ab = __expf(dtv * ac[n]);
      h[n] = ab * h[n] + dx * sB[l][n];
    }
  }
  size_t base = (size_t)c * NSTATE + (size_t)d * NST;
#pragma unroll
  for (int n = 0; n < NST; ++n) hout[base + n] = h[n];
  dts[(size_t)c * DINs + d] = dtsum;
}

// ---------------- Pass B: combine chunk summaries -> hpref ----------------
__global__ __launch_bounds__(256) void k_scanB(
    const float* __restrict__ dts, const float* __restrict__ Alog,
    const float* __restrict__ hout, float* __restrict__ hpref) {
  int s = blockIdx.x * 256 + threadIdx.x;   // 0..NSTATE-1; d = s>>4
  const float ac = -__expf(Alog[s]);
  float h = 0.f;
#pragma unroll 8
  for (int c = 0; c < NC; ++c) {
    size_t idx = (size_t)c * NSTATE + s;
    float a = __expf(dts[(size_t)c * DINs + (s >> 4)] * ac);
    float b = hout[idx];
    hpref[idx] = h;
    h = a * h + b;
  }
}

// ---------------- Pass C: recompute with true h_in, fuse y + D*xc + silu(z) gate ----------------
__global__ __launch_bounds__(256) void k_scanC(
    const float* __restrict__ dtf, const float* __restrict__ xdbl,
    const float* __restrict__ xc, const float* __restrict__ xz,
    const float* __restrict__ Alog, const float* __restrict__ Dp,
    const float* __restrict__ hpref, u16* __restrict__ ybar) {
  __shared__ float sB[CL][NST], sC[CL][NST];
  const int t = threadIdx.x;
  const int d = blockIdx.x * 256 + t;
  const int c = blockIdx.y;
  {
    int l = t >> 4, n = t & 15;
    sB[l][n] = xdbl[(size_t)(c * CL + l) * NXD + RDT + n];
    sC[l][n] = xdbl[(size_t)(c * CL + l) * NXD + RDT + NST + n];
  }
  __syncthreads();
  float ac[NST];
#pragma unroll
  for (int i = 0; i < 4; ++i) {
    float4 v = *(const float4*)&Alog[(size_t)d * NST + i * 4];
    ac[i * 4 + 0] = -__expf(v.x); ac[i * 4 + 1] = -__expf(v.y);
    ac[i * 4 + 2] = -__expf(v.z); ac[i * 4 + 3] = -__expf(v.w);
  }
  float h[NST];
  size_t base = (size_t)c * NSTATE + (size_t)d * NST;
#pragma unroll
  for (int i = 0; i < 4; ++i)
    *(float4*)&h[i * 4] = *(const float4*)&hpref[base + i * 4];
  const float Dv = Dp[d];
#pragma unroll
  for (int l = 0; l < CL; ++l) {
    float dtv = dtf[(size_t)(c * CL + l) * DINs + d];
    float xcv = xc[(size_t)(c * CL + l) * DINs + d];
    float zv  = xz[(size_t)(c * CL + l) * (2 * DINs) + DINs + d];
    float dx = dtv * xcv;
    float y0 = Dv * xcv, y1 = 0.f, y2 = 0.f, y3 = 0.f;
#pragma unroll
    for (int n = 0; n < NST; n += 4) {
      float ab0 = __expf(dtv * ac[n]);
      float ab1 = __expf(dtv * ac[n + 1]);
      float ab2 = __expf(dtv * ac[n + 2]);
      float ab3 = __expf(dtv * ac[n + 3]);
      h[n]     = ab0 * h[n]     + dx * sB[l][n];
      h[n + 1] = ab1 * h[n + 1] + dx * sB[l][n + 1];
      h[n + 2] = ab2 * h[n + 2] + dx * sB[l][n + 2];
      h[n + 3] = ab3 * h[n + 3] + dx * sB[l][n + 3];
      y0 += h[n] * sC[l][n];
      y1 += h[n + 1] * sC[l][n + 1];
      y2 += h[n + 2] * sC[l][n + 2];
      y3 += h[n + 3] * sC[l][n + 3];
    }
    float y = (y0 + y1) + (y2 + y3);
    float sz = zv / (1.f + __expf(-zv));
    ybar[(size_t)(c * CL + l) * DINs + d] = f2bf(y * sz);
  }
}

// ---------------- launch ----------------
extern "C" void kernel_launch(void* const* d_in, const int* in_sizes, int n_in,
                              void* d_out, int out_size, void* d_ws, size_t ws_size,
                              hipStream_t stream) {
  (void)in_sizes; (void)n_in; (void)out_size; (void)ws_size;
  const float* x      = (const float*)d_in[0];
  const float* W_in   = (const float*)d_in[1];
  const float* conv_w = (const float*)d_in[2];
  const float* conv_b = (const float*)d_in[3];
  const float* W_x    = (const float*)d_in[4];
  const float* W_dt   = (const float*)d_in[5];
  const float* b_dt   = (const float*)d_in[6];
  const float* A_log  = (const float*)d_in[7];
  const float* D_par  = (const float*)d_in[8];
  const float* W_out  = (const float*)d_in[9];
  float* out = (float*)d_out;

  const size_t MB = 1u << 20;
  char* wsb = (char*)d_ws;
  u16*   x_bf    = (u16*)(wsb + 0);          // 2 MB   (dead after GEMM1)
  u16*   win_bf  = (u16*)(wsb + 2 * MB);     // 8 MB   (dead after GEMM1)
  u16*   a2      = (u16*)(wsb + 0);          // 12 MB  (written by conv, AFTER GEMM1)
  u16*   wout_bf = (u16*)(wsb + 12 * MB);    // 4 MB
  float* xz      = (float*)(wsb + 16 * MB);  // 16 MB
  float* xc      = (float*)(wsb + 32 * MB);  // 8 MB
  u16*   b2      = (u16*)(wsb + 40 * MB);    // 1.2 MB
  float* part    = (float*)(wsb + 42 * MB);  // 3 MB
  float* xdbl    = (float*)(wsb + 45 * MB);  // 384 KB
  float* dtf     = (float*)(wsb + 46 * MB);  // 8 MB
  u16*   ybar    = (u16*)(wsb + 54 * MB);    // 4 MB
  float* hout    = (float*)(wsb + 58 * MB);  // 8 MB
  float* hpref   = (float*)(wsb + 66 * MB);  // 8 MB
  float* dts     = (float*)(wsb + 74 * MB);  // 0.5 MB
  float* g4p     = (float*)(wsb + 75 * MB);  // 8 MB (gemm4 K-split parts) -> total 83 MB

  k_prep<<<1024, 256, 0, stream>>>(x, W_in, W_out, W_x, x_bf, win_bf, wout_bf, b2);

  // GEMM1: xz[L][4096] = x * W_in^T   (grid 16x32, BK=64, 16 iters)
  k_gemm_db<64, 128, 64, 1><<<dim3(LSEQ / 64, (2 * DINs) / 128, 1), 256, 0, stream>>>(
      x_bf, win_bf, xz, LSEQ, 2 * DINs, DMs);

  k_conv<<<dim3(DINs / 256, LSEQ / 16), 256, 0, stream>>>(xz, conv_w, conv_b, xc, a2);

  // GEMM2: split-bf16 MFMA, K' = 6144, K-split 8 (grid 16x8, 12 iters)
  k_gemm2db<<<dim3(LSEQ / 64, KS2), 256, 0, stream>>>(a2, b2, part);
  k_red8<<<(LSEQ * NXD) / 256, 256, 0, stream>>>(part, xdbl);

  k_gemm3<<<dim3(DINs / 256, LSEQ / 16), 256, 0, stream>>>(xdbl, W_dt, b_dt, dtf);

  // chunked scan
  k_scanA<<<dim3(DINs / 256, NC), 256, 0, stream>>>(dtf, xdbl, xc, A_log, hout, dts);
  k_scanB<<<NSTATE / 256, 256, 0, stream>>>(dts, A_log, hout, hpref);
  k_scanC<<<dim3(DINs / 256, NC), 256, 0, stream>>>(dtf, xdbl, xc, xz, A_log, D_par,
                                                    hpref, ybar);

  // GEMM4: out = ybar * W_out^T   (grid 16x16x2 K-split, 16 iters) + reduce
  k_gemm_db<64, 64, 64, 2><<<dim3(LSEQ / 64, DMs / 64, 2), 256, 0, stream>>>(
      ybar, wout_bf, g4p, LSEQ, DMs, DINs);
  k_add2<<<(DMs * LSEQ / 4) / 256, 256, 0, stream>>>(g4p, out, (DMs * LSEQ) / 4);
}